// Round 1
// baseline (203.133 us; speedup 1.0000x reference)
//
#include <hip/hip_runtime.h>
#include <math.h>

#define KDIM 8192
#define NDIM 512
#define NT   128   // KDIM / BK, BK = 64

typedef float  f32x4  __attribute__((ext_vector_type(4)));
typedef __bf16 bf16x8 __attribute__((ext_vector_type(8)));
typedef __bf16 bf16x4 __attribute__((ext_vector_type(4)));

// C[m,n] = tanh( sum_k A[m,k] * W[n,k] ),  A: 8192x8192 f32, W: 512x8192 f32.
// BM=BN=128, BK=64, 512 threads = 8 waves (2x4), 16x16x32 bf16 MFMA,
// per-wave 64x32 output = acc[4][2] fragments. Double-buffered LDS,
// reg-staged fp32->bf16 conversion, XOR-swizzled LDS (T2), XCD swizzle (T1).
__global__ __launch_bounds__(512)
void gemm_bt_tanh(const float* __restrict__ A, const float* __restrict__ W,
                  float* __restrict__ C) {
  // XCD-chunked block swizzle: 32 consecutive logical blocks per XCD.
  const int bid  = blockIdx.x;            // grid = 256 (divisible by 8: bijective)
  const int lbid = (bid & 7) * 32 + (bid >> 3);
  const int bm = lbid >> 2;                // 64 M-tiles
  const int bn = lbid & 3;                 // 4  N-tiles
  const int tid  = threadIdx.x;
  const int lane = tid & 63;
  const int wid  = tid >> 6;
  const int wm = wid >> 2;                 // 0..1  (64-row slab)
  const int wn = wid & 3;                  // 0..3  (32-col slab)

  __shared__ __align__(16) __bf16 sA[2][128 * 64];
  __shared__ __align__(16) __bf16 sB[2][128 * 64];

  const float* A0 = A + (size_t)(bm * 128) * KDIM;
  const float* B0 = W + (size_t)(bn * 128) * KDIM;

  // ---- staging addresses: 4 float4 loads per thread per matrix per K-step
  const float* pA[4];
  const float* pB[4];
  int we[4];  // swizzled LDS element index for the 4x-bf16 write
  #pragma unroll
  for (int i = 0; i < 4; ++i) {
    int idx = i * 512 + tid;       // 0..2047 over the 128x64 tile (float4 units)
    int r = idx >> 4;              // row 0..127
    int c = (idx & 15) << 2;       // col 0..60 (step 4)
    we[i] = (r << 6) + (c ^ ((r & 7) << 3));   // elem idx, byte ^= (r&7)<<4
    pA[i] = A0 + (size_t)r * KDIM + c;
    pB[i] = B0 + (size_t)r * KDIM + c;
  }

  // ---- fragment read offsets (same swizzle; row&7 == lane&7 here)
  const int swz   = (lane & 7) << 3;
  const int koff0 = (((lane >> 4) << 3) +  0) ^ swz;
  const int koff1 = (((lane >> 4) << 3) + 32) ^ swz;
  int rbA[4], rbB[2];
  #pragma unroll
  for (int mi = 0; mi < 4; ++mi) rbA[mi] = (wm * 64 + mi * 16 + (lane & 15)) << 6;
  #pragma unroll
  for (int ni = 0; ni < 2; ++ni) rbB[ni] = (wn * 32 + ni * 16 + (lane & 15)) << 6;

  f32x4 acc[4][2];
  #pragma unroll
  for (int mi = 0; mi < 4; ++mi)
    #pragma unroll
    for (int ni = 0; ni < 2; ++ni)
      acc[mi][ni] = (f32x4){0.f, 0.f, 0.f, 0.f};

  float4 rA[4], rB[4];

  // ---- prologue: stage K-tile 0
  #pragma unroll
  for (int i = 0; i < 4; ++i) {
    rA[i] = *(const float4*)(pA[i]);
    rB[i] = *(const float4*)(pB[i]);
  }
  #pragma unroll
  for (int i = 0; i < 4; ++i) {
    bf16x4 ua = {(__bf16)rA[i].x, (__bf16)rA[i].y, (__bf16)rA[i].z, (__bf16)rA[i].w};
    bf16x4 ub = {(__bf16)rB[i].x, (__bf16)rB[i].y, (__bf16)rB[i].z, (__bf16)rB[i].w};
    *(bf16x4*)&sA[0][we[i]] = ua;
    *(bf16x4*)&sB[0][we[i]] = ub;
  }
  __syncthreads();

  for (int t = 0; t < NT; ++t) {
    const int cur = t & 1;
    // issue next tile's global loads first: HBM latency hides under MFMA
    if (t + 1 < NT) {
      #pragma unroll
      for (int i = 0; i < 4; ++i) {
        rA[i] = *(const float4*)(pA[i] + (size_t)(t + 1) * 64);
        rB[i] = *(const float4*)(pB[i] + (size_t)(t + 1) * 64);
      }
    }
    // compute on buffer `cur`
    {
      bf16x8 af[4], bfr[2];
      #pragma unroll
      for (int mi = 0; mi < 4; ++mi) af[mi]  = *(const bf16x8*)&sA[cur][rbA[mi] + koff0];
      #pragma unroll
      for (int ni = 0; ni < 2; ++ni) bfr[ni] = *(const bf16x8*)&sB[cur][rbB[ni] + koff0];
      #pragma unroll
      for (int mi = 0; mi < 4; ++mi)
        #pragma unroll
        for (int ni = 0; ni < 2; ++ni)
          acc[mi][ni] = __builtin_amdgcn_mfma_f32_16x16x32_bf16(af[mi], bfr[ni], acc[mi][ni], 0, 0, 0);
      #pragma unroll
      for (int mi = 0; mi < 4; ++mi) af[mi]  = *(const bf16x8*)&sA[cur][rbA[mi] + koff1];
      #pragma unroll
      for (int ni = 0; ni < 2; ++ni) bfr[ni] = *(const bf16x8*)&sB[cur][rbB[ni] + koff1];
      #pragma unroll
      for (int mi = 0; mi < 4; ++mi)
        #pragma unroll
        for (int ni = 0; ni < 2; ++ni)
          acc[mi][ni] = __builtin_amdgcn_mfma_f32_16x16x32_bf16(af[mi], bfr[ni], acc[mi][ni], 0, 0, 0);
    }
    // convert + write next tile into the other buffer (overlaps nothing it reads)
    if (t + 1 < NT) {
      #pragma unroll
      for (int i = 0; i < 4; ++i) {
        bf16x4 ua = {(__bf16)rA[i].x, (__bf16)rA[i].y, (__bf16)rA[i].z, (__bf16)rA[i].w};
        bf16x4 ub = {(__bf16)rB[i].x, (__bf16)rB[i].y, (__bf16)rB[i].z, (__bf16)rB[i].w};
        *(bf16x4*)&sA[cur ^ 1][we[i]] = ua;
        *(bf16x4*)&sB[cur ^ 1][we[i]] = ub;
      }
    }
    __syncthreads();
  }

  // ---- epilogue: tanh + store fp32
  // C/D frag layout (m89): col = lane&15, row = (lane>>4)*4 + reg
  float* Cb = C + (size_t)(bm * 128 + wm * 64) * NDIM + bn * 128 + wn * 32;
  #pragma unroll
  for (int mi = 0; mi < 4; ++mi)
    #pragma unroll
    for (int ni = 0; ni < 2; ++ni)
      #pragma unroll
      for (int r = 0; r < 4; ++r) {
        int row = mi * 16 + ((lane >> 4) << 2) + r;
        int col = ni * 16 + (lane & 15);
        Cb[(size_t)row * NDIM + col] = tanhf(acc[mi][ni][r]);
      }
}

extern "C" void kernel_launch(void* const* d_in, const int* in_sizes, int n_in,
                              void* d_out, int out_size, void* d_ws, size_t ws_size,
                              hipStream_t stream) {
  const float* x = (const float*)d_in[0];  // [16*512, 8192] f32
  const float* W = (const float*)d_in[1];  // [512, 8192]    f32
  float* out = (float*)d_out;              // [8192, 512]    f32
  gemm_bt_tanh<<<dim3(256), dim3(512), 0, stream>>>(x, W, out);
}

// Round 2
// 186.407 us; speedup vs baseline: 1.0897x; 1.0897x over previous
//
#include <hip/hip_runtime.h>
#include <math.h>

#define KDIM 8192
#define NDIM 512
#define BM 128
#define BN 64
#define BK 64
#define NT (KDIM / BK)   // 128

typedef float  f32x4  __attribute__((ext_vector_type(4)));
typedef __bf16 bf16x8 __attribute__((ext_vector_type(8)));
typedef __bf16 bf16x4 __attribute__((ext_vector_type(4)));

// C[m,n] = tanh( sum_k A[m,k] * W[n,k] ), A: 8192x8192 f32, W: 512x8192 f32.
// BM=128, BN=64, BK=64, 512 threads = 8 waves (4M x 2N), wave tile 32x32,
// 16x16x32 bf16 MFMA, acc 2x2. Grid 512 = 2 blocks/CU. Depth-2 register
// prefetch (two named buffers, x2-unrolled loop), double-buffered LDS,
// XOR-swizzle (T2, verified conflict-free R1), XCD-chunked swizzle (T1).
__global__ __launch_bounds__(512, 4)
void gemm_bt_tanh(const float* __restrict__ A, const float* __restrict__ W,
                  float* __restrict__ C) {
  const int bid  = blockIdx.x;              // 512 blocks (div by 8: bijective)
  const int lbid = (bid & 7) * 64 + (bid >> 3);
  const int bm = lbid >> 3;                 // 64 M-tiles; 8 consecutive lbid
  const int bn = lbid & 7;                  // share one A-panel on one XCD
  const int tid  = threadIdx.x;
  const int lane = tid & 63;
  const int wid  = tid >> 6;
  const int wm = wid >> 1;                  // 0..3 (32-row slab)
  const int wn = wid & 1;                   // 0..1 (32-col slab)

  __shared__ __align__(16) __bf16 sA[2][BM * BK];  // 16 KB each
  __shared__ __align__(16) __bf16 sB[2][BN * BK];  // 8 KB each

  const float* A0 = A + (size_t)(bm * BM) * KDIM;
  const float* B0 = W + (size_t)(bn * BN) * KDIM;

  // ---- staging: A 4 float4/thread, B 2 float4/thread per K-step
  const float* pA[4]; int wa[4];
  const float* pB[2]; int wb[2];
  #pragma unroll
  for (int i = 0; i < 4; ++i) {
    int idx = i * 512 + tid;        // 128 rows x 16 float4
    int r = idx >> 4, c = (idx & 15) << 2;
    wa[i] = (r << 6) + (c ^ ((r & 7) << 3));
    pA[i] = A0 + (size_t)r * KDIM + c;
  }
  #pragma unroll
  for (int i = 0; i < 2; ++i) {
    int idx = i * 512 + tid;        // 64 rows x 16 float4
    int r = idx >> 4, c = (idx & 15) << 2;
    wb[i] = (r << 6) + (c ^ ((r & 7) << 3));
    pB[i] = B0 + (size_t)r * KDIM + c;
  }

  // ---- fragment read bases (row&7 == lane&7, matches write swizzle)
  const int rbA0 = (wm * 32 +  0 + (lane & 15)) << 6;
  const int rbA1 = (wm * 32 + 16 + (lane & 15)) << 6;
  const int rbB0 = (wn * 32 +  0 + (lane & 15)) << 6;
  const int rbB1 = (wn * 32 + 16 + (lane & 15)) << 6;

  f32x4 acc00 = {0,0,0,0}, acc01 = {0,0,0,0}, acc10 = {0,0,0,0}, acc11 = {0,0,0,0};

  float4 ra0[4], rb0[2], ra1[4], rb1[2];

  auto issue0 = [&](int t) {
    size_t off = (size_t)t * BK;
    #pragma unroll
    for (int i = 0; i < 4; ++i) ra0[i] = *(const float4*)(pA[i] + off);
    #pragma unroll
    for (int i = 0; i < 2; ++i) rb0[i] = *(const float4*)(pB[i] + off);
  };
  auto issue1 = [&](int t) {
    size_t off = (size_t)t * BK;
    #pragma unroll
    for (int i = 0; i < 4; ++i) ra1[i] = *(const float4*)(pA[i] + off);
    #pragma unroll
    for (int i = 0; i < 2; ++i) rb1[i] = *(const float4*)(pB[i] + off);
  };
  auto write0 = [&](int buf) {
    #pragma unroll
    for (int i = 0; i < 4; ++i) {
      bf16x4 u = {(__bf16)ra0[i].x, (__bf16)ra0[i].y, (__bf16)ra0[i].z, (__bf16)ra0[i].w};
      *(bf16x4*)&sA[buf][wa[i]] = u;
    }
    #pragma unroll
    for (int i = 0; i < 2; ++i) {
      bf16x4 u = {(__bf16)rb0[i].x, (__bf16)rb0[i].y, (__bf16)rb0[i].z, (__bf16)rb0[i].w};
      *(bf16x4*)&sB[buf][wb[i]] = u;
    }
  };
  auto write1 = [&](int buf) {
    #pragma unroll
    for (int i = 0; i < 4; ++i) {
      bf16x4 u = {(__bf16)ra1[i].x, (__bf16)ra1[i].y, (__bf16)ra1[i].z, (__bf16)ra1[i].w};
      *(bf16x4*)&sA[buf][wa[i]] = u;
    }
    #pragma unroll
    for (int i = 0; i < 2; ++i) {
      bf16x4 u = {(__bf16)rb1[i].x, (__bf16)rb1[i].y, (__bf16)rb1[i].z, (__bf16)rb1[i].w};
      *(bf16x4*)&sB[buf][wb[i]] = u;
    }
  };
  auto compute = [&](int buf) {
    #pragma unroll
    for (int kh = 0; kh < 2; ++kh) {
      const int ko = (((lane >> 4) << 3) + kh * 32) ^ ((lane & 7) << 3);
      bf16x8 a0 = *(const bf16x8*)&sA[buf][rbA0 + ko];
      bf16x8 a1 = *(const bf16x8*)&sA[buf][rbA1 + ko];
      bf16x8 b0 = *(const bf16x8*)&sB[buf][rbB0 + ko];
      bf16x8 b1 = *(const bf16x8*)&sB[buf][rbB1 + ko];
      acc00 = __builtin_amdgcn_mfma_f32_16x16x32_bf16(a0, b0, acc00, 0, 0, 0);
      acc01 = __builtin_amdgcn_mfma_f32_16x16x32_bf16(a0, b1, acc01, 0, 0, 0);
      acc10 = __builtin_amdgcn_mfma_f32_16x16x32_bf16(a1, b0, acc10, 0, 0, 0);
      acc11 = __builtin_amdgcn_mfma_f32_16x16x32_bf16(a1, b1, acc11, 0, 0, 0);
    }
  };

  // ---- prologue: tiles 0 (→LDS0) and 1 (in regs, in flight)
  issue0(0);
  issue1(1);
  write0(0);
  __syncthreads();

  // ---- main loop: unrolled x2, static buffer names
  // invariant at top: LDS0 = tile t, ra1/rb1 = tile t+1 in flight
  for (int t = 0; t < NT - 3; t += 2) {
    // even: prefetch t+2, compute t from LDS0, write t+1 -> LDS1
    issue0(t + 2);
    compute(0);
    write1(1);                       // compiler waits vmcnt(6) for ra1/rb1
    __syncthreads();
    // odd: prefetch t+3, compute t+1 from LDS1, write t+2 -> LDS0
    issue1(t + 3);
    compute(1);
    write0(0);
    __syncthreads();
  }
  // tail: LDS0 = tile 126, ra1/rb1 = tile 127 in flight
  compute(0);
  write1(1);
  __syncthreads();
  compute(1);

  // ---- epilogue: tanh + fp32 store
  // C/D frag layout (m89): col = lane&15, row = (lane>>4)*4 + reg
  float* Cb = C + (size_t)(bm * BM + wm * 32) * NDIM + bn * BN + wn * 32;
  const int r0 = (lane >> 4) << 2;
  const int c0 = lane & 15;
  #pragma unroll
  for (int r = 0; r < 4; ++r) {
    Cb[(size_t)(r0 + r) * NDIM + c0]            = tanhf(acc00[r]);
    Cb[(size_t)(r0 + r) * NDIM + 16 + c0]       = tanhf(acc01[r]);
    Cb[(size_t)(16 + r0 + r) * NDIM + c0]       = tanhf(acc10[r]);
    Cb[(size_t)(16 + r0 + r) * NDIM + 16 + c0]  = tanhf(acc11[r]);
  }
}

extern "C" void kernel_launch(void* const* d_in, const int* in_sizes, int n_in,
                              void* d_out, int out_size, void* d_ws, size_t ws_size,
                              hipStream_t stream) {
  const float* x = (const float*)d_in[0];  // [8192, 8192] f32 (B*S rows)
  const float* W = (const float*)d_in[1];  // [512, 8192]  f32
  float* out = (float*)d_out;              // [8192, 512]  f32
  gemm_bt_tanh<<<dim3(512), dim3(512), 0, stream>>>(x, W, out);
}

// Round 3
// 97.380 us; speedup vs baseline: 2.0860x; 1.9142x over previous
//
#include <hip/hip_runtime.h>
#include <math.h>

#define M_ROWS 8192   // B*S
#define KDIM   8192   // V
#define NDIM   512    // D

typedef float  f32x4  __attribute__((ext_vector_type(4)));
typedef __bf16 bf16x8 __attribute__((ext_vector_type(8)));

// ---------------------------------------------------------------------------
// Kernel 1: W [512, 8192] f32  ->  WT [8192, 512] bf16 (in d_ws, 8 MB).
// 64x64 LDS tile transpose; coalesced f32 reads, 16B bf16x8 writes.
__global__ __launch_bounds__(256)
void transpose_w(const float* __restrict__ W, __bf16* __restrict__ WT) {
  __shared__ float tile[64][68];          // +4 pad: kills bank-conflict stride
  const int t  = threadIdx.x;
  const int v0 = (blockIdx.x & 127) << 6; // 128 v-tiles
  const int d0 = (blockIdx.x >> 7) << 6;  // 8 d-tiles
  #pragma unroll
  for (int i = 0; i < 4; ++i) {
    int idx = i * 256 + t;                // 0..1023 float4s of the 64x64 tile
    int r = idx >> 4;                     // d-row 0..63
    int c = (idx & 15) << 2;              // v-col 0..60
    float4 val = *(const float4*)(W + (size_t)(d0 + r) * KDIM + v0 + c);
    tile[r][c + 0] = val.x; tile[r][c + 1] = val.y;
    tile[r][c + 2] = val.z; tile[r][c + 3] = val.w;
  }
  __syncthreads();
  #pragma unroll
  for (int i = 0; i < 2; ++i) {
    int idx = i * 256 + t;                // 0..511 bf16x8s of the 64x64 output
    int vr = idx >> 3;                    // v-row 0..63
    int d8 = (idx & 7) << 3;              // d-col 0..56
    bf16x8 u;
    #pragma unroll
    for (int j = 0; j < 8; ++j) u[j] = (__bf16)tile[d8 + j][vr];
    *(bf16x8*)(WT + (size_t)(v0 + vr) * NDIM + d0 + d8) = u;
  }
}

// ---------------------------------------------------------------------------
// Kernel 2: sparse-aware SpMM + tanh.  One wave per output row m.
//   C[m, :] = tanh( sum over nonzero A[m,v] of A[m,v] * WT[v, :] )
// Exact for ANY density (ballot enumerates actual nonzeros); fast because
// inputs are ~1% nonzero.  A-scan is the HBM stream (256 MB, coalesced
// 1 KB/wave/iter); WT gathers (1 KB/wave each) hit L2/L3 (WT = 8 MB).
// Lane `l` owns output columns l*8..l*8+7, accumulated in 8 f32 registers.
__global__ __launch_bounds__(256, 8)
void spmm_tanh(const float* __restrict__ A, const __bf16* __restrict__ WT,
               float* __restrict__ C) {
  const int lane = threadIdx.x & 63;
  const int m    = blockIdx.x * 4 + (threadIdx.x >> 6);
  const float* arow = A + (size_t)m * KDIM;
  const char*  wtb  = (const char*)WT;

  float a0 = 0.f, a1 = 0.f, a2 = 0.f, a3 = 0.f,
        a4 = 0.f, a5 = 0.f, a6 = 0.f, a7 = 0.f;

  // depth-1 prefetch of the scan stream
  f32x4 av = *(const f32x4*)(arow + lane * 4);
  for (int it = 0; it < KDIM / 256; ++it) {
    f32x4 avn;
    if (it + 1 < KDIM / 256)
      avn = *(const f32x4*)(arow + (it + 1) * 256 + lane * 4);
    #pragma unroll
    for (int j = 0; j < 4; ++j) {
      unsigned long long mask = __ballot(av[j] != 0.0f);
      while (mask) {                       // wave-uniform loop
        int src = __builtin_ctzll(mask);
        mask &= mask - 1;
        float a = __shfl(av[j], src, 64);
        int   v = it * 256 + src * 4 + j;
        uint4 w = *(const uint4*)(wtb + (size_t)v * (NDIM * 2) + lane * 16);
        // expand 8 bf16 -> f32 (shift/mask, no cvt needed)
        float w0 = __uint_as_float(w.x << 16);
        float w1 = __uint_as_float(w.x & 0xffff0000u);
        float w2 = __uint_as_float(w.y << 16);
        float w3 = __uint_as_float(w.y & 0xffff0000u);
        float w4 = __uint_as_float(w.z << 16);
        float w5 = __uint_as_float(w.z & 0xffff0000u);
        float w6 = __uint_as_float(w.w << 16);
        float w7 = __uint_as_float(w.w & 0xffff0000u);
        a0 = fmaf(a, w0, a0); a1 = fmaf(a, w1, a1);
        a2 = fmaf(a, w2, a2); a3 = fmaf(a, w3, a3);
        a4 = fmaf(a, w4, a4); a5 = fmaf(a, w5, a5);
        a6 = fmaf(a, w6, a6); a7 = fmaf(a, w7, a7);
      }
    }
    av = avn;
  }

  float* crow = C + (size_t)m * NDIM + lane * 8;
  float4 o0 = {tanhf(a0), tanhf(a1), tanhf(a2), tanhf(a3)};
  float4 o1 = {tanhf(a4), tanhf(a5), tanhf(a6), tanhf(a7)};
  *(float4*)(crow + 0) = o0;
  *(float4*)(crow + 4) = o1;
}

// ---------------------------------------------------------------------------
extern "C" void kernel_launch(void* const* d_in, const int* in_sizes, int n_in,
                              void* d_out, int out_size, void* d_ws, size_t ws_size,
                              hipStream_t stream) {
  const float* x = (const float*)d_in[0];  // [8192, 8192] f32 (B*S rows)
  const float* W = (const float*)d_in[1];  // [512, 8192]  f32
  float* out = (float*)d_out;              // [8192, 512]  f32
  __bf16* WT = (__bf16*)d_ws;              // [8192, 512]  bf16, 8 MB scratch

  transpose_w<<<dim3(1024), dim3(256), 0, stream>>>(W, WT);
  spmm_tanh  <<<dim3(M_ROWS / 4), dim3(256), 0, stream>>>(x, WT, out);
}